// Round 5
// baseline (3638.018 us; speedup 1.0000x reference)
//
#include <hip/hip_runtime.h>
#include <hip/hip_bf16.h>

typedef __attribute__((ext_vector_type(8))) short short8;
typedef __attribute__((ext_vector_type(8))) unsigned short ushort8;
typedef __attribute__((ext_vector_type(4))) float f32x4;
typedef __attribute__((ext_vector_type(4))) int int4v;
typedef __attribute__((ext_vector_type(4))) short short4v;

#define NB 256      // batch rows
#define NS 256      // timesteps
#define NH 512      // hidden/state dim (D == H == 512)
#define NOUT 128
#define XROW 513    // x last-dim stride

#define NCL 16      // clusters
#define RPC 16      // rows per cluster
#define BPC 4       // blocks per cluster
#define UBS 128     // u-dims per block
#define LPAD 520    // padded LDS row (bf16): 1040B stride

// ---- workspace layout (bytes) ----
#define OFF_DTS   0
#define OFF_Y0    4096
#define OFF_U0    (OFF_Y0 + NB*NH*4)
#define OFF_M     (OFF_U0 + NB*NH*4)
#define OFF_C     (OFF_M + NH*NH*2)
#define OFF_P     (OFF_C + 4096)
#define OFF_HG    (OFF_P + NOUT*NH*4)                // 16 cl * 2 buf * 16*512 f32 (stamped) = 1 MB
#define HG_BYTES  (NCL*2*RPC*NH*4)
#define OFF_HACC  (OFF_HG + HG_BYTES)

static __device__ __forceinline__ unsigned bf16bits(float x) {
  return (unsigned)__builtin_bit_cast(unsigned short, __float2bfloat16(x));
}

// Cross-block traffic: sc0 sc1 (device coherence point) — proven in R2/R4.
static __device__ __forceinline__ void g_store16(void* addr, int4v v) {
  asm volatile("global_store_dwordx4 %0, %1, off sc0 sc1" :: "v"(addr), "v"(v) : "memory");
}
static __device__ __forceinline__ int4v g_load16(const void* addr) {  // no wait
  int4v v;
  asm volatile("global_load_dwordx4 %0, %1, off sc0 sc1" : "=v"(v) : "v"(addr) : "memory");
  return v;
}
static __device__ __forceinline__ void wait_vm0() {
  asm volatile("s_waitcnt vmcnt(0)" ::: "memory");
}

// fast tanh: (e^{2x}-1)/(e^{2x}+1), clamp |x|<=15
static __device__ __forceinline__ float tanh_fast(float x) {
  x = fminf(fmaxf(x, -15.f), 15.f);
  float e = __expf(2.f * x);
  return (e - 1.f) * __builtin_amdgcn_rcpf(e + 1.f);
}

// -------------------- small prep kernels --------------------

__global__ void k_dts(const float* __restrict__ x, float* __restrict__ dts) {
  int s = threadIdx.x;
  if (s < NS - 1) dts[s] = x[(s + 1) * XROW] - x[s * XROW];
  if (s == NS - 1) dts[NS - 1] = x[(NS - 1) * XROW] - x[0];  // sum_dt (telescoping)
}

__global__ void k_y0(const float* __restrict__ x, float* __restrict__ y0) {
  int b = blockIdx.x;
  const float* src = x + (size_t)b * NS * XROW + (size_t)(NS - 1) * XROW + 1;
  for (int d = threadIdx.x; d < NH; d += blockDim.x) y0[b * NH + d] = src[d];
}

__global__ void k_c(const float* __restrict__ W1, const float* __restrict__ b2,
                    float* __restrict__ c) {
  int i = blockIdx.x * blockDim.x + threadIdx.x;
  if (i < NH) {
    float s = 0.f;
    for (int d = 0; d < NH; ++d) s += W1[i * NH + d] * b2[d];
    c[i] = s;
  }
}

__global__ void k_mm_nn_bf16(const float* __restrict__ A, const float* __restrict__ Bm,
                             __hip_bfloat16* __restrict__ C, int N, int K) {
  __shared__ float As[16][17], Bs[16][17];
  int tx = threadIdx.x & 15, ty = threadIdx.x >> 4;
  int m = blockIdx.y * 16 + ty, n = blockIdx.x * 16 + tx;
  float acc = 0.f;
  for (int k0 = 0; k0 < K; k0 += 16) {
    As[ty][tx] = A[m * K + k0 + tx];
    Bs[ty][tx] = Bm[(size_t)(k0 + ty) * N + n];
    __syncthreads();
#pragma unroll
    for (int kk = 0; kk < 16; ++kk) acc += As[ty][kk] * Bs[kk][tx];
    __syncthreads();
  }
  C[m * N + n] = __float2bfloat16(acc);
}

__global__ void k_mm_nn_f32(const float* __restrict__ A, const float* __restrict__ Bm,
                            float* __restrict__ C, int N, int K) {
  __shared__ float As[16][17], Bs[16][17];
  int tx = threadIdx.x & 15, ty = threadIdx.x >> 4;
  int m = blockIdx.y * 16 + ty, n = blockIdx.x * 16 + tx;
  float acc = 0.f;
  for (int k0 = 0; k0 < K; k0 += 16) {
    As[ty][tx] = A[m * K + k0 + tx];
    Bs[ty][tx] = Bm[(size_t)(k0 + ty) * N + n];
    __syncthreads();
#pragma unroll
    for (int kk = 0; kk < 16; ++kk) acc += As[ty][kk] * Bs[kk][tx];
    __syncthreads();
  }
  C[m * N + n] = acc;
}

__global__ void k_mm_nt_f32(const float* __restrict__ A, const float* __restrict__ Bm,
                            float* __restrict__ C, int N, int K) {
  __shared__ float As[16][17], Bs[16][17];
  int tx = threadIdx.x & 15, ty = threadIdx.x >> 4;
  int m = blockIdx.y * 16 + ty;
  int n0 = blockIdx.x * 16;
  float acc = 0.f;
  for (int k0 = 0; k0 < K; k0 += 16) {
    As[ty][tx] = A[m * K + k0 + tx];
    Bs[ty][tx] = Bm[(size_t)(n0 + ty) * K + k0 + tx];
    __syncthreads();
#pragma unroll
    for (int kk = 0; kk < 16; ++kk) acc += As[ty][kk] * Bs[tx][kk];
    __syncthreads();
  }
  C[m * N + n0 + tx] = acc;
}

// -------------------- main ODE integration kernel --------------------
// 64 blocks = 16 clusters x 4 blocks. Stamped-data exchange: each exchanged
// f32 word = (h_bf16 << 16) | ((sidx+1) & 0xffff). Producer stores with
// sc0 sc1 and does NOT wait; consumer poll-loads the remote chunks and
// accepts when every word carries the current stamp (dword stores are
// single-copy atomic -> stamp valid => h valid). No flags, no store-ack,
// poll and gather are the same load: ~1 coherence RTT per stage.
// hG is memset to 0 at launch start (kills cross-replay ABA); parity
// double-buffer kills within-launch ABA (stale stamp = sidx-1 != sidx+1).

__global__ __launch_bounds__(256) void k_main(
    const float* __restrict__ u0, const __hip_bfloat16* __restrict__ Mg,
    const float* __restrict__ cg, const float* __restrict__ b1g,
    const float* __restrict__ dtsg,
    float* __restrict__ hG, float* __restrict__ Hacc)
{
  __shared__ __hip_bfloat16 Mlds[UBS][LPAD];   // 130 KB
  __shared__ __hip_bfloat16 hlds[RPC][LPAD];   // 16.25 KB
  __shared__ float dtl[NS];
  __shared__ int okf[4];

  const int tid = threadIdx.x;
  const int bx = blockIdx.x;
  const int xcd = bx & 7, slot = bx >> 3;
  const int cl = xcd + ((slot >> 2) << 3);   // cluster members share bid mod 8 (XCD heuristic)
  const int jb = slot & 3;
  const int lane = tid & 63, wv = tid >> 6;
  const int r = lane & 15, g4 = lane >> 4;
  const int row0 = cl * RPC;
  const int ub = jb * UBS;
  const int rr = tid >> 4, sl = tid & 15;     // gather assignment

  // stage M slice into LDS (rows [ub, ub+128) of M)
  for (int i = tid; i < UBS * 64; i += 256) {
    int row = i >> 6, ch = (i & 63) * 8;
    *(ushort8*)&Mlds[row][ch] = *(const ushort8*)(Mg + (size_t)(ub + row) * NH + ch);
  }
  if (tid < NS) dtl[tid] = dtsg[tid];

  // per-lane state: (udim = ub + wv*32 + t*16 + g4*4 + j, batch row = row0 + r)
  const int udl0 = wv * 32 + g4 * 4;
  float u[2][4], Wa[2][4], Hs[2][4], Ht[2][4], hr[2][4], wp[2][4];
  float b1r[2][4], cr[2][4];
#pragma unroll
  for (int t = 0; t < 2; ++t)
#pragma unroll
    for (int j = 0; j < 4; ++j) {
      int ud = ub + udl0 + t * 16 + j;
      u[t][j] = u0[(row0 + r) * NH + ud];
      b1r[t][j] = b1g[ud];
      cr[t][j] = cg[ud];
      Ht[t][j] = 0.f; wp[t][j] = 0.f; Wa[t][j] = 0.f; Hs[t][j] = 0.f;
    }
  __syncthreads();

  int sidx = 0;
  for (int step = 0; step < NS - 1; ++step) {
    float dt = dtl[step];
#pragma unroll 1
    for (int st = 0; st < 4; ++st, ++sidx) {
      float gam = (st == 0) ? 0.f : ((st == 3) ? dt : 0.5f * dt);
      unsigned stamp = (unsigned)(sidx + 1);
      // h = tanh(u + gam*w_prev + b1)
#pragma unroll
      for (int t = 0; t < 2; ++t)
#pragma unroll
        for (int j = 0; j < 4; ++j)
          hr[t][j] = tanh_fast(u[t][j] + gam * wp[t][j] + b1r[t][j]);

      int par = sidx & 1;
      float* hgp = hG + (size_t)(cl * 2 + par) * RPC * NH;
      // publish own h: stamped f32 to global (no wait) + bf16 to LDS
#pragma unroll
      for (int t = 0; t < 2; ++t) {
        int col = ub + udl0 + t * 16;
        unsigned hb0 = bf16bits(hr[t][0]), hb1 = bf16bits(hr[t][1]);
        unsigned hb2 = bf16bits(hr[t][2]), hb3 = bf16bits(hr[t][3]);
        int4v sv;
        sv.x = (int)((hb0 << 16) | stamp);
        sv.y = (int)((hb1 << 16) | stamp);
        sv.z = (int)((hb2 << 16) | stamp);
        sv.w = (int)((hb3 << 16) | stamp);
        g_store16(hgp + r * NH + col, sv);
        short4v pk;
        pk.x = (short)hb0; pk.y = (short)hb1; pk.z = (short)hb2; pk.w = (short)hb3;
        *(short4v*)&hlds[r][col] = pk;
      }
      __syncthreads();                 // own h visible in LDS to all waves

      // own-k MFMA (overlaps producers' store flight)
      f32x4 acc0 = {0.f, 0.f, 0.f, 0.f}, acc1 = {0.f, 0.f, 0.f, 0.f};
#pragma unroll
      for (int q = 0; q < 4; ++q) {
        int kc = ub + q * 32 + g4 * 8;
        short8 bf = *(const short8*)&hlds[r][kc];
        short8 a0 = *(const short8*)&Mlds[wv * 32 + r][kc];
        short8 a1 = *(const short8*)&Mlds[wv * 32 + 16 + r][kc];
        acc0 = __builtin_amdgcn_mfma_f32_16x16x32_bf16(a0, bf, acc0, 0, 0, 0);
        acc1 = __builtin_amdgcn_mfma_f32_16x16x32_bf16(a1, bf, acc1, 0, 0, 0);
      }

      // poll-gather the 3 remote stamped chunks (16 rows x 128 f32 each)
      int4v dv[6];
      for (;;) {
#pragma unroll
        for (int m = 0; m < 3; ++m) {
          int jr = (jb + 1 + m) & 3;
          const float* base = hgp + rr * NH + jr * UBS + sl * 8;
          dv[2 * m]     = g_load16(base);
          dv[2 * m + 1] = g_load16(base + 4);
        }
        wait_vm0();
        bool ok = true;
#pragma unroll
        for (int q = 0; q < 6; ++q)
          ok &= (((unsigned)dv[q].x & 0xffffu) == stamp) &
                (((unsigned)dv[q].y & 0xffffu) == stamp) &
                (((unsigned)dv[q].z & 0xffffu) == stamp) &
                (((unsigned)dv[q].w & 0xffffu) == stamp);
        bool wok = __all((int)ok);
        if (lane == 0) okf[wv] = wok ? 1 : 0;
        __syncthreads();
        if (okf[0] & okf[1] & okf[2] & okf[3]) break;
        __syncthreads();
        __builtin_amdgcn_s_sleep(1);
      }
      // strip stamps, pack to bf16, write remote cols into LDS
#pragma unroll
      for (int m = 0; m < 3; ++m) {
        int jr = (jb + 1 + m) & 3;
        int4v a = dv[2 * m], b = dv[2 * m + 1];
        int4v pk;
        pk.x = (int)(((unsigned)a.x >> 16) | ((unsigned)a.y & 0xffff0000u));
        pk.y = (int)(((unsigned)a.z >> 16) | ((unsigned)a.w & 0xffff0000u));
        pk.z = (int)(((unsigned)b.x >> 16) | ((unsigned)b.y & 0xffff0000u));
        pk.w = (int)(((unsigned)b.z >> 16) | ((unsigned)b.w & 0xffff0000u));
        *(int4v*)&hlds[rr][jr * UBS + sl * 8] = pk;
      }
      __syncthreads();

      // remote-k MFMA
#pragma unroll 1
      for (int m = 0; m < 3; ++m) {
        int jr = (jb + 1 + m) & 3;
#pragma unroll
        for (int q = 0; q < 4; ++q) {
          int kc = jr * UBS + q * 32 + g4 * 8;
          short8 bf = *(const short8*)&hlds[r][kc];
          short8 a0 = *(const short8*)&Mlds[wv * 32 + r][kc];
          short8 a1 = *(const short8*)&Mlds[wv * 32 + 16 + r][kc];
          acc0 = __builtin_amdgcn_mfma_f32_16x16x32_bf16(a0, bf, acc0, 0, 0, 0);
          acc1 = __builtin_amdgcn_mfma_f32_16x16x32_bf16(a1, bf, acc1, 0, 0, 0);
        }
      }

      float wc[2][4];
#pragma unroll
      for (int j = 0; j < 4; ++j) { wc[0][j] = acc0[j] + cr[0][j]; wc[1][j] = acc1[j] + cr[1][j]; }

      // RK4 bookkeeping
      float cw = (st == 0 || st == 3) ? 1.f : 2.f;
#pragma unroll
      for (int t = 0; t < 2; ++t)
#pragma unroll
        for (int j = 0; j < 4; ++j) {
          if (st == 0) { Wa[t][j] = wc[t][j]; Hs[t][j] = hr[t][j]; }
          else { Wa[t][j] += cw * wc[t][j]; Hs[t][j] += cw * hr[t][j]; }
          wp[t][j] = wc[t][j];
        }
      if (st == 3) {
        float f6 = dt * (1.f / 6.f);
#pragma unroll
        for (int t = 0; t < 2; ++t)
#pragma unroll
          for (int j = 0; j < 4; ++j) {
            u[t][j] += f6 * Wa[t][j];
            Ht[t][j] += f6 * Hs[t][j];
          }
      }
      __syncthreads();   // protect hlds (this stage's reads) from next stage's writes
    }
  }

  // write out H accumulator
#pragma unroll
  for (int t = 0; t < 2; ++t)
#pragma unroll
    for (int j = 0; j < 4; ++j)
      Hacc[(row0 + r) * NH + ub + udl0 + t * 16 + j] = Ht[t][j];
}

// -------------------- epilogue --------------------
__global__ void k_epi(const float* __restrict__ y0, const float* __restrict__ Hacc,
                      const float* __restrict__ P, const float* __restrict__ Wout,
                      const float* __restrict__ b2, const float* __restrict__ bout,
                      const float* __restrict__ dtsg, float* __restrict__ out)
{
  __shared__ float ys[NH], hs[NH];
  int rr = blockIdx.x, o = threadIdx.x;
  float sdt = dtsg[NS - 1];
  for (int i = threadIdx.x; i < NH; i += blockDim.x) {
    ys[i] = y0[rr * NH + i] + sdt * b2[i];
    hs[i] = Hacc[rr * NH + i];
  }
  __syncthreads();
  float s = bout[o];
  const float* wr = Wout + o * NH;
  const float* pr = P + o * NH;
  for (int d = 0; d < NH; ++d) s += wr[d] * ys[d];
  for (int h = 0; h < NH; ++h) s += pr[h] * hs[h];
  out[rr * NOUT + o] = s;
}

// -------------------- launch --------------------

extern "C" void kernel_launch(void* const* d_in, const int* in_sizes, int n_in,
                              void* d_out, int out_size, void* d_ws, size_t ws_size,
                              hipStream_t stream) {
  const float* x    = (const float*)d_in[0];
  const float* W1   = (const float*)d_in[1];
  const float* b1   = (const float*)d_in[2];
  const float* W2   = (const float*)d_in[3];
  const float* b2   = (const float*)d_in[4];
  const float* Wout = (const float*)d_in[5];
  const float* bout = (const float*)d_in[6];
  float* out = (float*)d_out;

  char* ws = (char*)d_ws;
  float*          dts  = (float*)(ws + OFF_DTS);
  float*          y0   = (float*)(ws + OFF_Y0);
  float*          u0   = (float*)(ws + OFF_U0);
  __hip_bfloat16* Mbf  = (__hip_bfloat16*)(ws + OFF_M);
  float*          cvec = (float*)(ws + OFF_C);
  float*          P    = (float*)(ws + OFF_P);
  float*          hG   = (float*)(ws + OFF_HG);
  float*          Hac  = (float*)(ws + OFF_HACC);

  hipMemsetAsync(hG, 0, HG_BYTES, stream);   // clear stamps (cross-replay ABA)

  k_dts<<<1, 256, 0, stream>>>(x, dts);
  k_y0 <<<NB, 256, 0, stream>>>(x, y0);
  k_c  <<<2, 256, 0, stream>>>(W1, b2, cvec);
  k_mm_nn_bf16<<<dim3(32, 32), 256, 0, stream>>>(W1, W2, Mbf, NH, NH);
  k_mm_nt_f32<<<dim3(32, 16), 256, 0, stream>>>(y0, W1, u0, NH, NH);
  k_mm_nn_f32<<<dim3(32, 8), 256, 0, stream>>>(Wout, W2, P, NH, NH);

  k_main<<<NCL * BPC, 256, 0, stream>>>(u0, Mbf, cvec, b1, dts, hG, Hac);

  k_epi<<<NB, NOUT, 0, stream>>>(y0, Hac, P, Wout, b2, bout, dts, out);
}

// Round 9
// 3347.126 us; speedup vs baseline: 1.0869x; 1.0869x over previous
//
#include <hip/hip_runtime.h>
#include <hip/hip_bf16.h>

typedef __attribute__((ext_vector_type(8))) short short8;
typedef __attribute__((ext_vector_type(8))) unsigned short ushort8;
typedef __attribute__((ext_vector_type(4))) float f32x4;
typedef __attribute__((ext_vector_type(4))) int int4v;
typedef __attribute__((ext_vector_type(4))) short short4v;

#define NB 256      // batch rows
#define NS 256      // timesteps
#define NH 512      // hidden/state dim (D == H == 512)
#define NOUT 128
#define XROW 513    // x last-dim stride

#define NCL 16      // clusters
#define RPC 16      // rows per cluster
#define BPC 4       // blocks per cluster
#define UBS 128     // u-dims per block
#define LPAD 520    // padded LDS row (bf16): 1040B stride

// ---- workspace layout (bytes) ----
#define OFF_DTS   0
#define OFF_Y0    4096
#define OFF_U0    (OFF_Y0 + NB*NH*4)
#define OFF_M     (OFF_U0 + NB*NH*4)
#define OFF_C     (OFF_M + NH*NH*2)
#define OFF_P     (OFF_C + 4096)
#define OFF_HG    (OFF_P + NOUT*NH*4)                // 16 cl * 2 buf * 16*512 f32 (stamped) = 1 MB
#define HG_BYTES  (NCL*2*RPC*NH*4)
#define OFF_HACC  (OFF_HG + HG_BYTES)

static __device__ __forceinline__ unsigned bf16bits(float x) {
  return (unsigned)__builtin_bit_cast(unsigned short, __float2bfloat16(x));
}

// Cross-block traffic: sc0 sc1 (device coherence point) — proven R2/R4/R5.
static __device__ __forceinline__ void g_store16(void* addr, int4v v) {
  asm volatile("global_store_dwordx4 %0, %1, off sc0 sc1" :: "v"(addr), "v"(v) : "memory");
}
static __device__ __forceinline__ unsigned g_load4w(const void* addr) {  // fused load+wait (R4-proven)
  unsigned v;
  asm volatile("global_load_dword %0, %1, off sc0 sc1\n\ts_waitcnt vmcnt(0)"
               : "=v"(v) : "v"(addr) : "memory");
  return v;
}
static __device__ __forceinline__ int4v g_load16(const void* addr) {  // no wait (R5-proven with tight wait)
  int4v v;
  asm volatile("global_load_dwordx4 %0, %1, off sc0 sc1" : "=v"(v) : "v"(addr) : "memory");
  return v;
}
static __device__ __forceinline__ void wait_vm0() {
  asm volatile("s_waitcnt vmcnt(0)" ::: "memory");
}

// fast tanh: (e^{2x}-1)/(e^{2x}+1), clamp |x|<=15  (R4-proven accuracy)
static __device__ __forceinline__ float tanh_fast(float x) {
  x = fminf(fmaxf(x, -15.f), 15.f);
  float e = __expf(2.f * x);
  return (e - 1.f) * __builtin_amdgcn_rcpf(e + 1.f);
}

// -------------------- small prep kernels --------------------

__global__ void k_dts(const float* __restrict__ x, float* __restrict__ dts) {
  int s = threadIdx.x;
  if (s < NS - 1) dts[s] = x[(s + 1) * XROW] - x[s * XROW];
  if (s == NS - 1) dts[NS - 1] = x[(NS - 1) * XROW] - x[0];  // sum_dt (telescoping)
}

__global__ void k_y0(const float* __restrict__ x, float* __restrict__ y0) {
  int b = blockIdx.x;
  const float* src = x + (size_t)b * NS * XROW + (size_t)(NS - 1) * XROW + 1;
  for (int d = threadIdx.x; d < NH; d += blockDim.x) y0[b * NH + d] = src[d];
}

__global__ void k_c(const float* __restrict__ W1, const float* __restrict__ b2,
                    float* __restrict__ c) {
  int i = blockIdx.x * blockDim.x + threadIdx.x;
  if (i < NH) {
    float s = 0.f;
    for (int d = 0; d < NH; ++d) s += W1[i * NH + d] * b2[d];
    c[i] = s;
  }
}

__global__ void k_mm_nn_bf16(const float* __restrict__ A, const float* __restrict__ Bm,
                             __hip_bfloat16* __restrict__ C, int N, int K) {
  __shared__ float As[16][17], Bs[16][17];
  int tx = threadIdx.x & 15, ty = threadIdx.x >> 4;
  int m = blockIdx.y * 16 + ty, n = blockIdx.x * 16 + tx;
  float acc = 0.f;
  for (int k0 = 0; k0 < K; k0 += 16) {
    As[ty][tx] = A[m * K + k0 + tx];
    Bs[ty][tx] = Bm[(size_t)(k0 + ty) * N + n];
    __syncthreads();
#pragma unroll
    for (int kk = 0; kk < 16; ++kk) acc += As[ty][kk] * Bs[kk][tx];
    __syncthreads();
  }
  C[m * N + n] = __float2bfloat16(acc);
}

__global__ void k_mm_nn_f32(const float* __restrict__ A, const float* __restrict__ Bm,
                            float* __restrict__ C, int N, int K) {
  __shared__ float As[16][17], Bs[16][17];
  int tx = threadIdx.x & 15, ty = threadIdx.x >> 4;
  int m = blockIdx.y * 16 + ty, n = blockIdx.x * 16 + tx;
  float acc = 0.f;
  for (int k0 = 0; k0 < K; k0 += 16) {
    As[ty][tx] = A[m * K + k0 + tx];
    Bs[ty][tx] = Bm[(size_t)(k0 + ty) * N + n];
    __syncthreads();
#pragma unroll
    for (int kk = 0; kk < 16; ++kk) acc += As[ty][kk] * Bs[kk][tx];
    __syncthreads();
  }
  C[m * N + n] = acc;
}

__global__ void k_mm_nt_f32(const float* __restrict__ A, const float* __restrict__ Bm,
                            float* __restrict__ C, int N, int K) {
  __shared__ float As[16][17], Bs[16][17];
  int tx = threadIdx.x & 15, ty = threadIdx.x >> 4;
  int m = blockIdx.y * 16 + ty;
  int n0 = blockIdx.x * 16;
  float acc = 0.f;
  for (int k0 = 0; k0 < K; k0 += 16) {
    As[ty][tx] = A[m * K + k0 + tx];
    Bs[ty][tx] = Bm[(size_t)(n0 + ty) * K + k0 + tx];
    __syncthreads();
#pragma unroll
    for (int kk = 0; kk < 16; ++kk) acc += As[ty][kk] * Bs[tx][kk];
    __syncthreads();
  }
  C[m * N + n0 + tx] = acc;
}

// -------------------- main ODE integration kernel --------------------
// R5's proven stage skeleton (passed on HW), with ONE insertion: a cheap
// 4-byte probe phase (R4's proven wave-local poll shape) between own-k MFMA
// and R5's bulk gather-validate consensus loop. Stamped word = (h_bf16<<16)|
// stamp; dword stores single-copy atomic; stale stamps (0 or stamp-2) cannot
// AND-combine into stamp. No producer ack, no flags.
// Per stage: tanh -> publish (fire-and-forget) -> [bar] -> own-k MFMA ->
// probe poll (4B/lane) -> bulk gather+validate (R5 consensus loop, ~1 iter)
// -> strip -> [bar] -> remote-k MFMA -> RK4 -> [bar].

__global__ __launch_bounds__(256) void k_main(
    const float* __restrict__ u0, const __hip_bfloat16* __restrict__ Mg,
    const float* __restrict__ cg, const float* __restrict__ b1g,
    const float* __restrict__ dtsg,
    float* __restrict__ hG, float* __restrict__ Hacc)
{
  __shared__ __hip_bfloat16 Mlds[UBS][LPAD];   // 130 KB
  __shared__ __hip_bfloat16 hlds[RPC][LPAD];   // 16.25 KB
  __shared__ float dtl[NS];
  __shared__ int okf[4];

  const int tid = threadIdx.x;
  const int bx = blockIdx.x;
  const int xcd = bx & 7, slot = bx >> 3;
  const int cl = xcd + ((slot >> 2) << 3);   // cluster members share bid mod 8 (XCD heuristic)
  const int jb = slot & 3;
  const int lane = tid & 63, wv = tid >> 6;
  const int r = lane & 15, g4 = lane >> 4;
  const int row0 = cl * RPC;
  const int ub = jb * UBS;
  const int rr = tid >> 4, sl = tid & 15;     // gather assignment

  // stage M slice into LDS (rows [ub, ub+128) of M)
  for (int i = tid; i < UBS * 64; i += 256) {
    int row = i >> 6, ch = (i & 63) * 8;
    *(ushort8*)&Mlds[row][ch] = *(const ushort8*)(Mg + (size_t)(ub + row) * NH + ch);
  }
  if (tid < NS) dtl[tid] = dtsg[tid];

  // per-lane state: (udim = ub + wv*32 + t*16 + g4*4 + j, batch row = row0 + r)
  const int udl0 = wv * 32 + g4 * 4;
  float u[2][4], Wa[2][4], Hs[2][4], Ht[2][4], hr[2][4], wp[2][4];
  float b1r[2][4], cr[2][4];
#pragma unroll
  for (int t = 0; t < 2; ++t)
#pragma unroll
    for (int j = 0; j < 4; ++j) {
      int ud = ub + udl0 + t * 16 + j;
      u[t][j] = u0[(row0 + r) * NH + ud];
      b1r[t][j] = b1g[ud];
      cr[t][j] = cg[ud];
      Ht[t][j] = 0.f; wp[t][j] = 0.f; Wa[t][j] = 0.f; Hs[t][j] = 0.f;
    }
  __syncthreads();

  // probe assignment: lanes 0-47 watch the last word of a row of one remote
  // chunk; lanes 48-63 duplicate chunk 0 (keeps __all over full wave).
  const int pm = (lane >> 4) & 3;
  const int pj0 = (pm < 3) ? pm : 0;
  const int jrp = (jb + 1 + pj0) & 3;

  int sidx = 0;
  for (int step = 0; step < NS - 1; ++step) {
    float dt = dtl[step];
#pragma unroll 1
    for (int st = 0; st < 4; ++st, ++sidx) {
      float gam = (st == 0) ? 0.f : ((st == 3) ? dt : 0.5f * dt);
      unsigned stamp = (unsigned)(sidx + 1);
      // h = tanh(u + gam*w_prev + b1)
#pragma unroll
      for (int t = 0; t < 2; ++t)
#pragma unroll
        for (int j = 0; j < 4; ++j)
          hr[t][j] = tanh_fast(u[t][j] + gam * wp[t][j] + b1r[t][j]);

      int par = sidx & 1;
      float* hgp = hG + (size_t)(cl * 2 + par) * RPC * NH;
      // publish own h: stamped f32 to global (fire-and-forget) + bf16 to LDS
#pragma unroll
      for (int t = 0; t < 2; ++t) {
        int col = ub + udl0 + t * 16;
        unsigned hb0 = bf16bits(hr[t][0]), hb1 = bf16bits(hr[t][1]);
        unsigned hb2 = bf16bits(hr[t][2]), hb3 = bf16bits(hr[t][3]);
        int4v sv;
        sv.x = (int)((hb0 << 16) | stamp);
        sv.y = (int)((hb1 << 16) | stamp);
        sv.z = (int)((hb2 << 16) | stamp);
        sv.w = (int)((hb3 << 16) | stamp);
        g_store16(hgp + r * NH + col, sv);
        short4v pk;
        pk.x = (short)hb0; pk.y = (short)hb1; pk.z = (short)hb2; pk.w = (short)hb3;
        *(short4v*)&hlds[r][col] = pk;
      }
      __syncthreads();                 // own h visible in LDS to all waves

      // own-k MFMA (overlaps producers' store flight)
      f32x4 acc0 = {0.f, 0.f, 0.f, 0.f}, acc1 = {0.f, 0.f, 0.f, 0.f};
#pragma unroll
      for (int q = 0; q < 4; ++q) {
        int kc = ub + q * 32 + g4 * 8;
        short8 bf = *(const short8*)&hlds[r][kc];
        short8 a0 = *(const short8*)&Mlds[wv * 32 + r][kc];
        short8 a1 = *(const short8*)&Mlds[wv * 32 + 16 + r][kc];
        acc0 = __builtin_amdgcn_mfma_f32_16x16x32_bf16(a0, bf, acc0, 0, 0, 0);
        acc1 = __builtin_amdgcn_mfma_f32_16x16x32_bf16(a1, bf, acc1, 0, 0, 0);
      }

      // probe phase (R4's proven poll shape): 4B stamped words, wave-local
      {
        const float* paddr = hgp + (lane & 15) * NH + jrp * UBS + 127;
        for (;;) {
          unsigned v = g_load4w(paddr);
          bool ok = ((v & 0xffffu) == stamp);
          if (__all((int)ok)) break;
          __builtin_amdgcn_s_sleep(1);
        }
      }

      // bulk gather + full validate (R5's proven consensus loop; ~1 iter)
      int4v dv[6];
      for (;;) {
#pragma unroll
        for (int m = 0; m < 3; ++m) {
          int jr = (jb + 1 + m) & 3;
          const float* base = hgp + rr * NH + jr * UBS + sl * 8;
          dv[2 * m]     = g_load16(base);
          dv[2 * m + 1] = g_load16(base + 4);
        }
        wait_vm0();
        bool ok = true;
#pragma unroll
        for (int q = 0; q < 6; ++q)
          ok &= (((unsigned)dv[q].x & 0xffffu) == stamp) &
                (((unsigned)dv[q].y & 0xffffu) == stamp) &
                (((unsigned)dv[q].z & 0xffffu) == stamp) &
                (((unsigned)dv[q].w & 0xffffu) == stamp);
        bool wok = __all((int)ok);
        if (lane == 0) okf[wv] = wok ? 1 : 0;
        __syncthreads();
        if (okf[0] & okf[1] & okf[2] & okf[3]) break;
        __syncthreads();
        __builtin_amdgcn_s_sleep(1);
      }
      // strip stamps, pack to bf16, write remote cols into LDS
#pragma unroll
      for (int m = 0; m < 3; ++m) {
        int jr = (jb + 1 + m) & 3;
        int4v a = dv[2 * m], b = dv[2 * m + 1];
        int4v pk;
        pk.x = (int)(((unsigned)a.x >> 16) | ((unsigned)a.y & 0xffff0000u));
        pk.y = (int)(((unsigned)a.z >> 16) | ((unsigned)a.w & 0xffff0000u));
        pk.z = (int)(((unsigned)b.x >> 16) | ((unsigned)b.y & 0xffff0000u));
        pk.w = (int)(((unsigned)b.z >> 16) | ((unsigned)b.w & 0xffff0000u));
        *(int4v*)&hlds[rr][jr * UBS + sl * 8] = pk;
      }
      __syncthreads();

      // remote-k MFMA
#pragma unroll 1
      for (int m = 0; m < 3; ++m) {
        int jr = (jb + 1 + m) & 3;
#pragma unroll
        for (int q = 0; q < 4; ++q) {
          int kc = jr * UBS + q * 32 + g4 * 8;
          short8 bf = *(const short8*)&hlds[r][kc];
          short8 a0 = *(const short8*)&Mlds[wv * 32 + r][kc];
          short8 a1 = *(const short8*)&Mlds[wv * 32 + 16 + r][kc];
          acc0 = __builtin_amdgcn_mfma_f32_16x16x32_bf16(a0, bf, acc0, 0, 0, 0);
          acc1 = __builtin_amdgcn_mfma_f32_16x16x32_bf16(a1, bf, acc1, 0, 0, 0);
        }
      }

      float wc[2][4];
#pragma unroll
      for (int j = 0; j < 4; ++j) { wc[0][j] = acc0[j] + cr[0][j]; wc[1][j] = acc1[j] + cr[1][j]; }

      // RK4 bookkeeping
      float cw = (st == 0 || st == 3) ? 1.f : 2.f;
#pragma unroll
      for (int t = 0; t < 2; ++t)
#pragma unroll
        for (int j = 0; j < 4; ++j) {
          if (st == 0) { Wa[t][j] = wc[t][j]; Hs[t][j] = hr[t][j]; }
          else { Wa[t][j] += cw * wc[t][j]; Hs[t][j] += cw * hr[t][j]; }
          wp[t][j] = wc[t][j];
        }
      if (st == 3) {
        float f6 = dt * (1.f / 6.f);
#pragma unroll
        for (int t = 0; t < 2; ++t)
#pragma unroll
          for (int j = 0; j < 4; ++j) {
            u[t][j] += f6 * Wa[t][j];
            Ht[t][j] += f6 * Hs[t][j];
          }
      }
      __syncthreads();   // protect hlds (this stage's reads) from next stage's writes
    }
  }

  // write out H accumulator
#pragma unroll
  for (int t = 0; t < 2; ++t)
#pragma unroll
    for (int j = 0; j < 4; ++j)
      Hacc[(row0 + r) * NH + ub + udl0 + t * 16 + j] = Ht[t][j];
}

// -------------------- epilogue --------------------
__global__ void k_epi(const float* __restrict__ y0, const float* __restrict__ Hacc,
                      const float* __restrict__ P, const float* __restrict__ Wout,
                      const float* __restrict__ b2, const float* __restrict__ bout,
                      const float* __restrict__ dtsg, float* __restrict__ out)
{
  __shared__ float ys[NH], hs[NH];
  int rr = blockIdx.x, o = threadIdx.x;
  float sdt = dtsg[NS - 1];
  for (int i = threadIdx.x; i < NH; i += blockDim.x) {
    ys[i] = y0[rr * NH + i] + sdt * b2[i];
    hs[i] = Hacc[rr * NH + i];
  }
  __syncthreads();
  float s = bout[o];
  const float* wr = Wout + o * NH;
  const float* pr = P + o * NH;
  for (int d = 0; d < NH; ++d) s += wr[d] * ys[d];
  for (int h = 0; h < NH; ++h) s += pr[h] * hs[h];
  out[rr * NOUT + o] = s;
}

// -------------------- launch --------------------

extern "C" void kernel_launch(void* const* d_in, const int* in_sizes, int n_in,
                              void* d_out, int out_size, void* d_ws, size_t ws_size,
                              hipStream_t stream) {
  const float* x    = (const float*)d_in[0];
  const float* W1   = (const float*)d_in[1];
  const float* b1   = (const float*)d_in[2];
  const float* W2   = (const float*)d_in[3];
  const float* b2   = (const float*)d_in[4];
  const float* Wout = (const float*)d_in[5];
  const float* bout = (const float*)d_in[6];
  float* out = (float*)d_out;

  char* ws = (char*)d_ws;
  float*          dts  = (float*)(ws + OFF_DTS);
  float*          y0   = (float*)(ws + OFF_Y0);
  float*          u0   = (float*)(ws + OFF_U0);
  __hip_bfloat16* Mbf  = (__hip_bfloat16*)(ws + OFF_M);
  float*          cvec = (float*)(ws + OFF_C);
  float*          P    = (float*)(ws + OFF_P);
  float*          hG   = (float*)(ws + OFF_HG);
  float*          Hac  = (float*)(ws + OFF_HACC);

  hipMemsetAsync(hG, 0, HG_BYTES, stream);   // clear stamps (cross-replay ABA)

  k_dts<<<1, 256, 0, stream>>>(x, dts);
  k_y0 <<<NB, 256, 0, stream>>>(x, y0);
  k_c  <<<2, 256, 0, stream>>>(W1, b2, cvec);
  k_mm_nn_bf16<<<dim3(32, 32), 256, 0, stream>>>(W1, W2, Mbf, NH, NH);
  k_mm_nt_f32<<<dim3(32, 16), 256, 0, stream>>>(y0, W1, u0, NH, NH);
  k_mm_nn_f32<<<dim3(32, 8), 256, 0, stream>>>(Wout, W2, P, NH, NH);

  k_main<<<NCL * BPC, 256, 0, stream>>>(u0, Mbf, cvec, b1, dts, hG, Hac);

  k_epi<<<NB, NOUT, 0, stream>>>(y0, Hac, P, Wout, b2, bout, dts, out);
}